// Round 11
// baseline (162.119 us; speedup 1.0000x reference)
//
#include <hip/hip_runtime.h>
#include <hip/hip_bf16.h>

#define NHEAD 8
#define KSZ 7
#define HS 56
#define WS 56
#define MTOK (2 * HS * WS)      // 6272 tokens

typedef unsigned short u16;
typedef unsigned int u32;

using bf16x8 = __attribute__((ext_vector_type(8))) short;
using f32x4  = __attribute__((ext_vector_type(4))) float;

static __device__ __forceinline__ u16 f2bf(float x) {
    u32 u = __float_as_uint(x);
    u += 0x7FFFu + ((u >> 16) & 1u);
    return (u16)(u >> 16);
}
static __device__ __forceinline__ float bf2f(u16 h) {
    return __uint_as_float(((u32)h) << 16);
}
// unpack u32 = (bf16 lo | bf16 hi<<16) -> two floats
static __device__ __forceinline__ float bflo(u32 w) { return __uint_as_float(w << 16); }
static __device__ __forceinline__ float bfhi(u32 w) { return __uint_as_float(w & 0xffff0000u); }

// global -> LDS direct copy, 16B per lane; LDS dest = wave-uniform base + lane*16
static __device__ __forceinline__ void gload16(const void* g, void* l) {
    __builtin_amdgcn_global_load_lds(
        (const __attribute__((address_space(1))) u32*)g,
        (__attribute__((address_space(3))) u32*)l, 16, 0, 0);
}

// bijective XCD-chunked block swizzle (m204)
static __device__ __forceinline__ int xcd_swz(int bid, int nwg) {
    const int q = nwg >> 3, r = nwg & 7;
    const int x = bid & 7, o = bid >> 3;
    return (x < r ? x * (q + 1) : r * (q + 1) + (x - r) * q) + o;
}

// ---------------------------------------------------------------------------
// Weights: W[K][N] fp32 -> WT[N][K] bf16, chunk-swizzled (16B chunk c of row n
// stored at c ^ (n&7) within each 64-elem k-segment).
// ---------------------------------------------------------------------------
__global__ __launch_bounds__(256) void cvt_w_kernel(
    const float* __restrict__ Wq, const float* __restrict__ Wkv,
    const float* __restrict__ Wp,
    u16* __restrict__ WT, u16* __restrict__ WpT_h, u16* __restrict__ WpT_l)
{
    __shared__ float Ts[32][33];
    const int b = blockIdx.x;
    const float* W; u16 *Th, *Tl; int N, tile; bool wantlo;
    if (b < 64)       { W = Wq;  Th = WT;             Tl = nullptr; N = 256; tile = b;       wantlo = false; }
    else if (b < 192) { W = Wkv; Th = WT + 256 * 256; Tl = nullptr; N = 512; tile = b - 64;  wantlo = false; }
    else              { W = Wp;  Th = WpT_h;          Tl = WpT_l;   N = 256; tile = b - 192; wantlo = true; }
    const int ntiles_n = N / 32;
    const int k0 = (tile / ntiles_n) * 32;
    const int n0 = (tile % ntiles_n) * 32;

    const int t = threadIdx.x;
    {
        const int kk = t >> 3, nn4 = (t & 7) * 4;
        float4 v = *reinterpret_cast<const float4*>(&W[(size_t)(k0 + kk) * N + n0 + nn4]);
        Ts[kk][nn4 + 0] = v.x; Ts[kk][nn4 + 1] = v.y;
        Ts[kk][nn4 + 2] = v.z; Ts[kk][nn4 + 3] = v.w;
    }
    __syncthreads();
    {
        const int nn = t >> 3, kk4 = (t & 7) * 4;
        const int n = n0 + nn;
        ushort4 h, l;
        u16* hp = &h.x; u16* lp = &l.x;
        #pragma unroll
        for (int i = 0; i < 4; ++i) {
            float x = Ts[kk4 + i][nn];
            u16 hb = f2bf(x);
            hp[i] = hb;
            lp[i] = f2bf(x - bf2f(hb));
        }
        const int kg = k0 + kk4;
        const int kphys = (kg & ~63) | ((((kg >> 3) & 7) ^ (n & 7)) << 3) | (kg & 7);
        const size_t o = (size_t)n * 256 + kphys;
        *reinterpret_cast<ushort4*>(&Th[o]) = h;
        if (wantlo) *reinterpret_cast<ushort4*>(&Tl[o]) = l;
    }
}

// ---------------------------------------------------------------------------
// Single-pass bf16 MFMA GEMM for the fused q/kv projections.
// 64M x 128N x 64K tile, 4 waves. A-path software-pipelined. B via
// global_load_lds from pre-swizzled WT. OUTPUT IS bf16 (q scaled +bq; kv +bkv).
// ---------------------------------------------------------------------------
__global__ __launch_bounds__(256) void gemm_qkv_kernel(
    const float* __restrict__ Aq, const float* __restrict__ Akv,
    const u16* __restrict__ WT,
    const float* __restrict__ biasq, const float* __restrict__ biaskv,
    u16* __restrict__ outq, u16* __restrict__ outkv, float scale)
{
    __shared__ __align__(16) u16 AS[64 * 64];
    __shared__ __align__(16) u16 BS[128 * 64];

    const int tid  = threadIdx.x;
    const int lane = tid & 63;
    const int w    = tid >> 6;          // wave 0..3 -> n-range w*32
    const int l16  = lane & 15;
    const int lhi  = lane >> 4;

    const int swz = xcd_swz(blockIdx.x, 6 * (MTOK / 64));   // 588 blocks
    const int n0 = (swz % 6) * 128;     // 0..767 combined col space
    const int m0 = (swz / 6) * 64;

    const float* A32 = (n0 < 256) ? Aq : Akv;

    const int arow = tid >> 2;
    const int akc  = (tid & 3) * 16;
    const int ac0  = (tid & 3) * 2;
    const int aswz = arow & 7;
    const float* aptr = &A32[(size_t)(m0 + arow) * 256 + akc];

    f32x4 acc[4][2];
    #pragma unroll
    for (int mi = 0; mi < 4; ++mi)
        #pragma unroll
        for (int ni = 0; ni < 2; ++ni) acc[mi][ni] = (f32x4){0.f, 0.f, 0.f, 0.f};

    float4 fa[4];
    #pragma unroll
    for (int v = 0; v < 4; ++v)
        fa[v] = *reinterpret_cast<const float4*>(aptr + v * 4);

    #pragma unroll
    for (int kt = 0; kt < 256; kt += 64) {
        __syncthreads();

        #pragma unroll
        for (int i = 0; i < 4; ++i) {
            const int rbase = w * 32 + i * 8;
            const size_t src = (size_t)(n0 + rbase + (lane >> 3)) * 256 + kt + (lane & 7) * 8;
            gload16(WT + src, &BS[rbase * 64]);
        }

        float4 fn[4];
        if (kt < 192) {
            #pragma unroll
            for (int v = 0; v < 4; ++v)
                fn[v] = *reinterpret_cast<const float4*>(aptr + kt + 64 + v * 4);
        }

        {
            const float f[16] = {fa[0].x, fa[0].y, fa[0].z, fa[0].w,
                                 fa[1].x, fa[1].y, fa[1].z, fa[1].w,
                                 fa[2].x, fa[2].y, fa[2].z, fa[2].w,
                                 fa[3].x, fa[3].y, fa[3].z, fa[3].w};
            union { u16 u[8]; uint4 v; } hx[2];
            #pragma unroll
            for (int e = 0; e < 16; ++e) hx[e >> 3].u[e & 7] = f2bf(f[e]);
            #pragma unroll
            for (int c = 0; c < 2; ++c) {
                const int o = arow * 64 + (((ac0 + c) ^ aswz) << 3);
                *reinterpret_cast<uint4*>(&AS[o]) = hx[c].v;
            }
        }

        __syncthreads();

        #pragma unroll
        for (int ks = 0; ks < 2; ++ks) {
            const int cph = ((ks * 4 + lhi) ^ (l16 & 7)) << 3;
            bf16x8 ah[4], bh[2];
            #pragma unroll
            for (int mi = 0; mi < 4; ++mi)
                ah[mi] = *reinterpret_cast<const bf16x8*>(&AS[(mi * 16 + l16) * 64 + cph]);
            #pragma unroll
            for (int ni = 0; ni < 2; ++ni)
                bh[ni] = *reinterpret_cast<const bf16x8*>(&BS[(w * 32 + ni * 16 + l16) * 64 + cph]);
            #pragma unroll
            for (int mi = 0; mi < 4; ++mi)
                #pragma unroll
                for (int ni = 0; ni < 2; ++ni)
                    acc[mi][ni] = __builtin_amdgcn_mfma_f32_16x16x32_bf16(
                        ah[mi], bh[ni], acc[mi][ni], 0, 0, 0);
        }

        #pragma unroll
        for (int v = 0; v < 4; ++v) fa[v] = fn[v];
    }

    const bool isq = (n0 < 256);
    u16* op = isq ? outq : outkv;
    const float* bs = isq ? biasq : biaskv;
    const int ldo = isq ? 256 : 512;
    const int coff = isq ? 0 : 256;
    const float sc = isq ? scale : 1.0f;

    #pragma unroll
    for (int ni = 0; ni < 2; ++ni) {
        const int col = n0 + w * 32 + ni * 16 + l16 - coff;
        const float bv = bs[col];
        #pragma unroll
        for (int mi = 0; mi < 4; ++mi) {
            const int row = m0 + mi * 16 + lhi * 4;
            #pragma unroll
            for (int rg = 0; rg < 4; ++rg)
                op[(size_t)(row + rg) * ldo + col] = f2bf((acc[mi][ni][rg] + bv) * sc);
        }
    }
}

// ---------------------------------------------------------------------------
// 3-pass hi/lo MFMA GEMM for the output projection (unchanged).
// ---------------------------------------------------------------------------
__global__ __launch_bounds__(256) void gemm_proj_kernel(
    const u16* __restrict__ Ah, const u16* __restrict__ Al,
    const u16* __restrict__ Wh, const u16* __restrict__ Wl,
    const float* __restrict__ bias, float* __restrict__ out)
{
    __shared__ __align__(16) u16 AhS[64 * 64];
    __shared__ __align__(16) u16 AlS[64 * 64];
    __shared__ __align__(16) u16 BhS[64 * 64];
    __shared__ __align__(16) u16 BlS[64 * 64];

    const int tid  = threadIdx.x;
    const int lane = tid & 63;
    const int w    = tid >> 6;
    const int wm   = w >> 1;
    const int wn   = w & 1;
    const int l16  = lane & 15;
    const int lhi  = lane >> 4;

    const int swz = xcd_swz(blockIdx.x, 4 * (MTOK / 64));   // 392 blocks
    const int n0 = (swz % 4) * 64;
    const int m0 = (swz / 4) * 64;

    f32x4 acc[2][2];
    #pragma unroll
    for (int mi = 0; mi < 2; ++mi)
        #pragma unroll
        for (int ni = 0; ni < 2; ++ni) acc[mi][ni] = (f32x4){0.f, 0.f, 0.f, 0.f};

    #pragma unroll
    for (int kt = 0; kt < 256; kt += 64) {
        __syncthreads();

        #pragma unroll
        for (int i = 0; i < 2; ++i) {
            const int rbase = w * 16 + i * 8;
            const size_t srcB = (size_t)(n0 + rbase + (lane >> 3)) * 256 + kt + (lane & 7) * 8;
            const size_t srcA = (size_t)(m0 + rbase + (lane >> 3)) * 256 + kt + (lane & 7) * 8;
            gload16(Wh + srcB, &BhS[rbase * 64]);
            gload16(Wl + srcB, &BlS[rbase * 64]);
            gload16(Ah + srcA, &AhS[rbase * 64]);
            gload16(Al + srcA, &AlS[rbase * 64]);
        }

        __syncthreads();

        #pragma unroll
        for (int ks = 0; ks < 2; ++ks) {
            const int cph = ((ks * 4 + lhi) ^ (l16 & 7)) << 3;
            bf16x8 ah[2], al[2], bh[2], bl[2];
            #pragma unroll
            for (int mi = 0; mi < 2; ++mi) {
                const int ro = (wm * 32 + mi * 16 + l16) * 64 + cph;
                ah[mi] = *reinterpret_cast<const bf16x8*>(&AhS[ro]);
                al[mi] = *reinterpret_cast<const bf16x8*>(&AlS[ro]);
            }
            #pragma unroll
            for (int ni = 0; ni < 2; ++ni) {
                const int ro = (wn * 32 + ni * 16 + l16) * 64 + cph;
                bh[ni] = *reinterpret_cast<const bf16x8*>(&BhS[ro]);
                bl[ni] = *reinterpret_cast<const bf16x8*>(&BlS[ro]);
            }
            #pragma unroll
            for (int mi = 0; mi < 2; ++mi)
                #pragma unroll
                for (int ni = 0; ni < 2; ++ni) {
                    acc[mi][ni] = __builtin_amdgcn_mfma_f32_16x16x32_bf16(
                        ah[mi], bh[ni], acc[mi][ni], 0, 0, 0);
                    acc[mi][ni] = __builtin_amdgcn_mfma_f32_16x16x32_bf16(
                        ah[mi], bl[ni], acc[mi][ni], 0, 0, 0);
                    acc[mi][ni] = __builtin_amdgcn_mfma_f32_16x16x32_bf16(
                        al[mi], bh[ni], acc[mi][ni], 0, 0, 0);
                }
        }
    }

    #pragma unroll
    for (int ni = 0; ni < 2; ++ni) {
        const int col = n0 + wn * 32 + ni * 16 + l16;
        const float bv = bias[col];
        #pragma unroll
        for (int mi = 0; mi < 2; ++mi) {
            const int row = m0 + wm * 32 + mi * 16 + lhi * 4;
            #pragma unroll
            for (int rg = 0; rg < 4; ++rg)
                out[(size_t)(row + rg) * 256 + col] = acc[mi][ni][rg] + bv;
        }
    }
}

// ---------------------------------------------------------------------------
// LDS-tiled neighborhood attention, bf16 K/V in LDS.
// SAME as Round-10 version except __launch_bounds__(256, 4): caps VGPR at 128
// (was 216 -> 2 waves/SIMD; now 4 waves/SIMD = 16 waves/CU, the f32 version's
// occupancy, with half the LDS bytes). Core live set ~85 regs, no spill.
// ---------------------------------------------------------------------------
#define REG 14
#define NREG (REG*REG)   // 196
#define KST16 40         // u16 stride per region row

__global__ __launch_bounds__(256, 4) void natten_kernel(
    const u16* __restrict__ qb, const u16* __restrict__ kvb,
    const float* __restrict__ rpb,
    u16* __restrict__ ohi, u16* __restrict__ olo)
{
    __shared__ __align__(16) u16 Ks16[NREG * KST16];
    __shared__ float Rp[169];

    const int tid = threadIdx.x;
    const int bid = blockIdx.x;             // 784 blocks
    const int head = bid & 7;
    const int idx  = bid >> 3;
    const int b    = idx / 49;
    const int t49  = idx % 49;
    const int ti0  = (t49 / 7) * 8;
    const int tj0  = (t49 % 7) * 8;

    int gr0 = ti0 - 3; gr0 = gr0 < 0 ? 0 : gr0; gr0 = gr0 > HS - REG ? HS - REG : gr0;
    int gc0 = tj0 - 3; gc0 = gc0 < 0 ? 0 : gc0; gc0 = gc0 > WS - REG ? WS - REG : gc0;

    const u16* kvb_head = kvb + (size_t)b * 3136 * 512 + head * 32;

    // ---- stage K (bf16): 4 iters of 64 rows, 4 lanes x 16B per row ----
    const int srow = tid >> 2;          // 0..63
    const int scol = (tid & 3) * 8;     // u16 offset (16B chunks)
    #pragma unroll
    for (int it = 0; it < 4; ++it) {
        const int rt = it * 64 + srow;
        if (rt < NREG) {
            const int g = (gr0 + rt / REG) * WS + (gc0 + rt % REG);
            const uint4 v = *reinterpret_cast<const uint4*>(
                kvb_head + (size_t)g * 512 + scol);
            *reinterpret_cast<uint4*>(&Ks16[rt * KST16 + scol]) = v;
        }
    }
    if (tid < 169) Rp[tid] = rpb[head * 169 + tid];

    const int tokl = tid >> 2;
    const int q4   = tid & 3;
    const int tr = tokl >> 3, tc = tokl & 7;
    const int i = ti0 + tr, j = tj0 + tc;

    int si = i - 3; si = si < 0 ? 0 : si; si = si > HS - KSZ ? HS - KSZ : si;
    int sj = j - 3; sj = sj < 0 ? 0 : sj; sj = sj > WS - KSZ ? WS - KSZ : sj;

    const int nb0 = (si - gr0) * REG + (sj - gc0);
    const int rb0 = (si - i + 6) * 13 + (sj - j + 6);
    const int tokflat = b * 3136 + i * WS + j;

    // ---- q (bf16) -> fp32 registers ----
    float qf[8];
    {
        const uint4 qv = *reinterpret_cast<const uint4*>(
            qb + (size_t)tokflat * 256 + head * 32 + q4 * 8);
        qf[0] = bflo(qv.x); qf[1] = bfhi(qv.x);
        qf[2] = bflo(qv.y); qf[3] = bfhi(qv.y);
        qf[4] = bflo(qv.z); qf[5] = bfhi(qv.z);
        qf[6] = bflo(qv.w); qf[7] = bfhi(qv.w);
    }

    __syncthreads();

    // ---- QK^T + bias ----
    float lg[49];
    #pragma unroll
    for (int ki = 0; ki < KSZ; ++ki) {
        #pragma unroll
        for (int kj = 0; kj < KSZ; ++kj) {
            const uint4 kv = *reinterpret_cast<const uint4*>(
                &Ks16[(nb0 + ki * REG + kj) * KST16 + q4 * 8]);
            float p;
            p = qf[0] * bflo(kv.x);
            p = fmaf(qf[1], bfhi(kv.x), p);
            p = fmaf(qf[2], bflo(kv.y), p);
            p = fmaf(qf[3], bfhi(kv.y), p);
            p = fmaf(qf[4], bflo(kv.z), p);
            p = fmaf(qf[5], bfhi(kv.z), p);
            p = fmaf(qf[6], bflo(kv.w), p);
            p = fmaf(qf[7], bfhi(kv.w), p);
            p += __shfl_xor(p, 1);
            p += __shfl_xor(p, 2);
            lg[ki * 7 + kj] = p + Rp[rb0 + ki * 13 + kj];
        }
    }

    // ---- softmax (register-only, redundant across the 4 quarter-lanes) ----
    float m = -1e30f;
    #pragma unroll
    for (int l = 0; l < 49; ++l) m = fmaxf(m, lg[l]);
    float ssum = 0.f;
    #pragma unroll
    for (int l = 0; l < 49; ++l) {
        const float e = __expf(lg[l] - m);
        lg[l] = e;
        ssum += e;
    }

    __syncthreads();   // all K reads done before V overwrites

    // ---- stage V (bf16, same buffer) ----
    #pragma unroll
    for (int it = 0; it < 4; ++it) {
        const int rt = it * 64 + srow;
        if (rt < NREG) {
            const int g = (gr0 + rt / REG) * WS + (gc0 + rt % REG);
            const uint4 v = *reinterpret_cast<const uint4*>(
                kvb_head + (size_t)g * 512 + 256 + scol);
            *reinterpret_cast<uint4*>(&Ks16[rt * KST16 + scol]) = v;
        }
    }
    __syncthreads();

    // ---- PV ----
    float acc[8] = {0.f, 0.f, 0.f, 0.f, 0.f, 0.f, 0.f, 0.f};
    #pragma unroll
    for (int ki = 0; ki < KSZ; ++ki) {
        #pragma unroll
        for (int kj = 0; kj < KSZ; ++kj) {
            const float w = lg[ki * 7 + kj];
            const uint4 vv = *reinterpret_cast<const uint4*>(
                &Ks16[(nb0 + ki * REG + kj) * KST16 + q4 * 8]);
            acc[0] = fmaf(w, bflo(vv.x), acc[0]);
            acc[1] = fmaf(w, bfhi(vv.x), acc[1]);
            acc[2] = fmaf(w, bflo(vv.y), acc[2]);
            acc[3] = fmaf(w, bfhi(vv.y), acc[3]);
            acc[4] = fmaf(w, bflo(vv.z), acc[4]);
            acc[5] = fmaf(w, bfhi(vv.z), acc[5]);
            acc[6] = fmaf(w, bflo(vv.w), acc[6]);
            acc[7] = fmaf(w, bfhi(vv.w), acc[7]);
        }
    }

    const float inv = 1.f / ssum;
    union { u16 u[8]; uint4 v; } ph, pl;
    #pragma unroll
    for (int d = 0; d < 8; ++d) {
        const float x = acc[d] * inv;
        const u16 hb = f2bf(x);
        ph.u[d] = hb;
        pl.u[d] = f2bf(x - bf2f(hb));
    }
    // chunk-swizzled store: k = head*32 + q4*8 -> chunk = head*4 + q4
    const int chunk = head * 4 + q4;
    const int seg = chunk >> 3, cin = chunk & 7;
    const int cphys = cin ^ (tokflat & 7);
    const size_t o = (size_t)tokflat * 256 + seg * 64 + cphys * 8;
    *reinterpret_cast<uint4*>(&ohi[o]) = ph.v;
    *reinterpret_cast<uint4*>(&olo[o]) = pl.v;
}

// ---------------------------------------------------------------------------
extern "C" void kernel_launch(void* const* d_in, const int* in_sizes, int n_in,
                              void* d_out, int out_size, void* d_ws, size_t ws_size,
                              hipStream_t stream) {
    const float* x_q   = (const float*)d_in[0];
    const float* x_k   = (const float*)d_in[1];
    const float* Wq    = (const float*)d_in[2];
    const float* bq    = (const float*)d_in[3];
    const float* Wkv   = (const float*)d_in[4];
    const float* bkv   = (const float*)d_in[5];
    const float* rpb   = (const float*)d_in[6];
    const float* Wproj = (const float*)d_in[7];
    const float* bproj = (const float*)d_in[8];
    float* out = (float*)d_out;

    const int M = MTOK;

    u16* qbuf  = (u16*)d_ws;                          // M*256 bf16
    u16* kvbuf = qbuf + (size_t)M * 256;              // M*512 bf16
    u16* at_hi = kvbuf + (size_t)M * 512;             // M*256 bf16 (swizzled)
    u16* at_lo = at_hi + (size_t)M * 256;
    u16* WT    = at_lo + (size_t)M * 256;             // 768*256 (hi)
    u16* WpT_h = WT + 768 * 256;                      // 256*256
    u16* WpT_l = WpT_h + 256 * 256;

    const float scale = 0.17677669529663687f;   // 32^-0.5

    dim3 blk(256);
    cvt_w_kernel<<<dim3(256), blk, 0, stream>>>(Wq, Wkv, Wproj, WT, WpT_h, WpT_l);

    // fused q + kv projection, single-pass bf16 -> bf16 outputs
    gemm_qkv_kernel<<<dim3(6 * (M / 64)), blk, 0, stream>>>(
        x_q, x_k, WT, bq, bkv, qbuf, kvbuf, scale);

    // neighborhood attention (bf16 LDS) -> swizzled hi/lo bf16
    natten_kernel<<<dim3(784), blk, 0, stream>>>(qbuf, kvbuf, rpb, at_hi, at_lo);

    // out = att @ Wproj + bproj (3-pass hi/lo)
    gemm_proj_kernel<<<dim3(4 * (M / 64)), blk, 0, stream>>>(
        at_hi, at_lo, WpT_h, WpT_l, bproj, out);
}

// Round 12
// 50.954 us; speedup vs baseline: 3.1817x; 3.1817x over previous
//
#include <hip/hip_runtime.h>
#include <hip/hip_bf16.h>

#define NHEAD 8
#define KSZ 7
#define HS 56
#define WS 56
#define MTOK (2 * HS * WS)      // 6272 tokens

typedef unsigned short u16;
typedef unsigned int u32;

using bf16x8 = __attribute__((ext_vector_type(8))) short;
using f32x4  = __attribute__((ext_vector_type(4))) float;

static __device__ __forceinline__ u16 f2bf(float x) {
    u32 u = __float_as_uint(x);
    u += 0x7FFFu + ((u >> 16) & 1u);
    return (u16)(u >> 16);
}
static __device__ __forceinline__ float bf2f(u16 h) {
    return __uint_as_float(((u32)h) << 16);
}

// global -> LDS direct copy, 16B per lane; LDS dest = wave-uniform base + lane*16
static __device__ __forceinline__ void gload16(const void* g, void* l) {
    __builtin_amdgcn_global_load_lds(
        (const __attribute__((address_space(1))) u32*)g,
        (__attribute__((address_space(3))) u32*)l, 16, 0, 0);
}

// bijective XCD-chunked block swizzle (m204)
static __device__ __forceinline__ int xcd_swz(int bid, int nwg) {
    const int q = nwg >> 3, r = nwg & 7;
    const int x = bid & 7, o = bid >> 3;
    return (x < r ? x * (q + 1) : r * (q + 1) + (x - r) * q) + o;
}

// ---------------------------------------------------------------------------
// Weights: W[K][N] fp32 -> WT[N][K] bf16, chunk-swizzled (16B chunk c of row n
// stored at c ^ (n&7) within each 64-elem k-segment).
// Wq -> WT rows 0..255 (hi), Wkv -> WT rows 256..767 (hi), Wproj -> hi + lo.
// ---------------------------------------------------------------------------
__global__ __launch_bounds__(256) void cvt_w_kernel(
    const float* __restrict__ Wq, const float* __restrict__ Wkv,
    const float* __restrict__ Wp,
    u16* __restrict__ WT, u16* __restrict__ WpT_h, u16* __restrict__ WpT_l)
{
    __shared__ float Ts[32][33];
    const int b = blockIdx.x;
    const float* W; u16 *Th, *Tl; int N, tile; bool wantlo;
    if (b < 64)       { W = Wq;  Th = WT;             Tl = nullptr; N = 256; tile = b;       wantlo = false; }
    else if (b < 192) { W = Wkv; Th = WT + 256 * 256; Tl = nullptr; N = 512; tile = b - 64;  wantlo = false; }
    else              { W = Wp;  Th = WpT_h;          Tl = WpT_l;   N = 256; tile = b - 192; wantlo = true; }
    const int ntiles_n = N / 32;
    const int k0 = (tile / ntiles_n) * 32;
    const int n0 = (tile % ntiles_n) * 32;

    const int t = threadIdx.x;
    {
        const int kk = t >> 3, nn4 = (t & 7) * 4;
        float4 v = *reinterpret_cast<const float4*>(&W[(size_t)(k0 + kk) * N + n0 + nn4]);
        Ts[kk][nn4 + 0] = v.x; Ts[kk][nn4 + 1] = v.y;
        Ts[kk][nn4 + 2] = v.z; Ts[kk][nn4 + 3] = v.w;
    }
    __syncthreads();
    {
        const int nn = t >> 3, kk4 = (t & 7) * 4;
        const int n = n0 + nn;
        ushort4 h, l;
        u16* hp = &h.x; u16* lp = &l.x;
        #pragma unroll
        for (int i = 0; i < 4; ++i) {
            float x = Ts[kk4 + i][nn];
            u16 hb = f2bf(x);
            hp[i] = hb;
            lp[i] = f2bf(x - bf2f(hb));
        }
        const int kg = k0 + kk4;
        const int kphys = (kg & ~63) | ((((kg >> 3) & 7) ^ (n & 7)) << 3) | (kg & 7);
        const size_t o = (size_t)n * 256 + kphys;
        *reinterpret_cast<ushort4*>(&Th[o]) = h;
        if (wantlo) *reinterpret_cast<ushort4*>(&Tl[o]) = l;
    }
}

// ---------------------------------------------------------------------------
// Single-pass bf16 MFMA GEMM for the fused q/kv projections (Round-9 exact).
// 64M x 128N x 64K tile, 4 waves. A-path software-pipelined. B via
// global_load_lds from pre-swizzled WT. f32 outputs.
// ---------------------------------------------------------------------------
__global__ __launch_bounds__(256) void gemm_qkv_kernel(
    const float* __restrict__ Aq, const float* __restrict__ Akv,
    const u16* __restrict__ WT,
    const float* __restrict__ biasq, const float* __restrict__ biaskv,
    float* __restrict__ outq, float* __restrict__ outkv, float scale)
{
    __shared__ __align__(16) u16 AS[64 * 64];
    __shared__ __align__(16) u16 BS[128 * 64];

    const int tid  = threadIdx.x;
    const int lane = tid & 63;
    const int w    = tid >> 6;          // wave 0..3 -> n-range w*32
    const int l16  = lane & 15;
    const int lhi  = lane >> 4;

    const int swz = xcd_swz(blockIdx.x, 6 * (MTOK / 64));   // 588 blocks
    const int n0 = (swz % 6) * 128;     // 0..767 combined col space
    const int m0 = (swz / 6) * 64;

    const float* A32 = (n0 < 256) ? Aq : Akv;

    const int arow = tid >> 2;
    const int akc  = (tid & 3) * 16;
    const int ac0  = (tid & 3) * 2;
    const int aswz = arow & 7;
    const float* aptr = &A32[(size_t)(m0 + arow) * 256 + akc];

    f32x4 acc[4][2];
    #pragma unroll
    for (int mi = 0; mi < 4; ++mi)
        #pragma unroll
        for (int ni = 0; ni < 2; ++ni) acc[mi][ni] = (f32x4){0.f, 0.f, 0.f, 0.f};

    float4 fa[4];
    #pragma unroll
    for (int v = 0; v < 4; ++v)
        fa[v] = *reinterpret_cast<const float4*>(aptr + v * 4);

    #pragma unroll
    for (int kt = 0; kt < 256; kt += 64) {
        __syncthreads();

        #pragma unroll
        for (int i = 0; i < 4; ++i) {
            const int rbase = w * 32 + i * 8;
            const size_t src = (size_t)(n0 + rbase + (lane >> 3)) * 256 + kt + (lane & 7) * 8;
            gload16(WT + src, &BS[rbase * 64]);
        }

        float4 fn[4];
        if (kt < 192) {
            #pragma unroll
            for (int v = 0; v < 4; ++v)
                fn[v] = *reinterpret_cast<const float4*>(aptr + kt + 64 + v * 4);
        }

        {
            const float f[16] = {fa[0].x, fa[0].y, fa[0].z, fa[0].w,
                                 fa[1].x, fa[1].y, fa[1].z, fa[1].w,
                                 fa[2].x, fa[2].y, fa[2].z, fa[2].w,
                                 fa[3].x, fa[3].y, fa[3].z, fa[3].w};
            union { u16 u[8]; uint4 v; } hx[2];
            #pragma unroll
            for (int e = 0; e < 16; ++e) hx[e >> 3].u[e & 7] = f2bf(f[e]);
            #pragma unroll
            for (int c = 0; c < 2; ++c) {
                const int o = arow * 64 + (((ac0 + c) ^ aswz) << 3);
                *reinterpret_cast<uint4*>(&AS[o]) = hx[c].v;
            }
        }

        __syncthreads();

        #pragma unroll
        for (int ks = 0; ks < 2; ++ks) {
            const int cph = ((ks * 4 + lhi) ^ (l16 & 7)) << 3;
            bf16x8 ah[4], bh[2];
            #pragma unroll
            for (int mi = 0; mi < 4; ++mi)
                ah[mi] = *reinterpret_cast<const bf16x8*>(&AS[(mi * 16 + l16) * 64 + cph]);
            #pragma unroll
            for (int ni = 0; ni < 2; ++ni)
                bh[ni] = *reinterpret_cast<const bf16x8*>(&BS[(w * 32 + ni * 16 + l16) * 64 + cph]);
            #pragma unroll
            for (int mi = 0; mi < 4; ++mi)
                #pragma unroll
                for (int ni = 0; ni < 2; ++ni)
                    acc[mi][ni] = __builtin_amdgcn_mfma_f32_16x16x32_bf16(
                        ah[mi], bh[ni], acc[mi][ni], 0, 0, 0);
        }

        #pragma unroll
        for (int v = 0; v < 4; ++v) fa[v] = fn[v];
    }

    const bool isq = (n0 < 256);
    float* op = isq ? outq : outkv;
    const float* bs = isq ? biasq : biaskv;
    const int ldo = isq ? 256 : 512;
    const int coff = isq ? 0 : 256;
    const float sc = isq ? scale : 1.0f;

    #pragma unroll
    for (int ni = 0; ni < 2; ++ni) {
        const int col = n0 + w * 32 + ni * 16 + l16 - coff;
        const float bv = bs[col];
        #pragma unroll
        for (int mi = 0; mi < 4; ++mi) {
            const int row = m0 + mi * 16 + lhi * 4;
            #pragma unroll
            for (int rg = 0; rg < 4; ++rg)
                op[(size_t)(row + rg) * ldo + col] = (acc[mi][ni][rg] + bv) * sc;
        }
    }
}

// ---------------------------------------------------------------------------
// 2-pass hi/lo MFMA GEMM for the output projection:
//   out ~= Ah·Bh + Ah·Bl  (the Al·Bh term is dropped; att's bf16 residue x
//   Wproj contributes ~1e-4 rms, within the error budget).
// 64M x 64N x 64K tile, 4 waves (2x2 of 32x32), 392 blocks, XCD-swizzled.
// A = natten's swizzled bf16 (hi only) via global_load_lds; B = WpT hi+lo.
// ---------------------------------------------------------------------------
__global__ __launch_bounds__(256) void gemm_proj_kernel(
    const u16* __restrict__ Ah,
    const u16* __restrict__ Wh, const u16* __restrict__ Wl,
    const float* __restrict__ bias, float* __restrict__ out)
{
    __shared__ __align__(16) u16 AhS[64 * 64];
    __shared__ __align__(16) u16 BhS[64 * 64];
    __shared__ __align__(16) u16 BlS[64 * 64];

    const int tid  = threadIdx.x;
    const int lane = tid & 63;
    const int w    = tid >> 6;
    const int wm   = w >> 1;
    const int wn   = w & 1;
    const int l16  = lane & 15;
    const int lhi  = lane >> 4;

    const int swz = xcd_swz(blockIdx.x, 4 * (MTOK / 64));   // 392 blocks
    const int n0 = (swz % 4) * 64;
    const int m0 = (swz / 4) * 64;

    f32x4 acc[2][2];
    #pragma unroll
    for (int mi = 0; mi < 2; ++mi)
        #pragma unroll
        for (int ni = 0; ni < 2; ++ni) acc[mi][ni] = (f32x4){0.f, 0.f, 0.f, 0.f};

    #pragma unroll
    for (int kt = 0; kt < 256; kt += 64) {
        __syncthreads();

        #pragma unroll
        for (int i = 0; i < 2; ++i) {
            const int rbase = w * 16 + i * 8;
            const size_t srcB = (size_t)(n0 + rbase + (lane >> 3)) * 256 + kt + (lane & 7) * 8;
            const size_t srcA = (size_t)(m0 + rbase + (lane >> 3)) * 256 + kt + (lane & 7) * 8;
            gload16(Wh + srcB, &BhS[rbase * 64]);
            gload16(Wl + srcB, &BlS[rbase * 64]);
            gload16(Ah + srcA, &AhS[rbase * 64]);
        }

        __syncthreads();

        #pragma unroll
        for (int ks = 0; ks < 2; ++ks) {
            const int cph = ((ks * 4 + lhi) ^ (l16 & 7)) << 3;
            bf16x8 ah[2], bh[2], bl[2];
            #pragma unroll
            for (int mi = 0; mi < 2; ++mi)
                ah[mi] = *reinterpret_cast<const bf16x8*>(&AhS[(wm * 32 + mi * 16 + l16) * 64 + cph]);
            #pragma unroll
            for (int ni = 0; ni < 2; ++ni) {
                const int ro = (wn * 32 + ni * 16 + l16) * 64 + cph;
                bh[ni] = *reinterpret_cast<const bf16x8*>(&BhS[ro]);
                bl[ni] = *reinterpret_cast<const bf16x8*>(&BlS[ro]);
            }
            #pragma unroll
            for (int mi = 0; mi < 2; ++mi)
                #pragma unroll
                for (int ni = 0; ni < 2; ++ni) {
                    acc[mi][ni] = __builtin_amdgcn_mfma_f32_16x16x32_bf16(
                        ah[mi], bh[ni], acc[mi][ni], 0, 0, 0);
                    acc[mi][ni] = __builtin_amdgcn_mfma_f32_16x16x32_bf16(
                        ah[mi], bl[ni], acc[mi][ni], 0, 0, 0);
                }
        }
    }

    #pragma unroll
    for (int ni = 0; ni < 2; ++ni) {
        const int col = n0 + wn * 32 + ni * 16 + l16;
        const float bv = bias[col];
        #pragma unroll
        for (int mi = 0; mi < 2; ++mi) {
            const int row = m0 + wm * 32 + mi * 16 + lhi * 4;
            #pragma unroll
            for (int rg = 0; rg < 4; ++rg)
                out[(size_t)(row + rg) * 256 + col] = acc[mi][ni][rg] + bv;
        }
    }
}

// ---------------------------------------------------------------------------
// LDS-tiled neighborhood attention (Round-9 f32 version, 92 VGPR known-good).
// Emits CHUNK-SWIZZLED bf16 (hi only) for the 2-pass proj GEMM.
// ---------------------------------------------------------------------------
#define REG 14
#define NREG (REG*REG)
#define KST 36

__global__ __launch_bounds__(256) void natten_kernel(
    const float* __restrict__ qb, const float* __restrict__ kvb,
    const float* __restrict__ rpb,
    u16* __restrict__ ohi)
{
    __shared__ float Ks[NREG * KST];
    __shared__ float Rp[169];

    const int tid = threadIdx.x;
    const int bid = blockIdx.x;             // 784 blocks
    const int head = bid & 7;
    const int idx  = bid >> 3;
    const int b    = idx / 49;
    const int t49  = idx % 49;
    const int ti0  = (t49 / 7) * 8;
    const int tj0  = (t49 % 7) * 8;

    int gr0 = ti0 - 3; gr0 = gr0 < 0 ? 0 : gr0; gr0 = gr0 > HS - REG ? HS - REG : gr0;
    int gc0 = tj0 - 3; gc0 = gc0 < 0 ? 0 : gc0; gc0 = gc0 > WS - REG ? WS - REG : gc0;

    const float* kvb_head = kvb + (size_t)b * 3136 * 512 + head * 32;

    #pragma unroll
    for (int rt0 = 0; rt0 < NREG; rt0 += 32) {
        const int rt = rt0 + (tid >> 3);
        if (rt < NREG) {
            const int r = rt / REG, c = rt % REG;
            const int g = (gr0 + r) * WS + (gc0 + c);
            const float4 v = *reinterpret_cast<const float4*>(
                kvb_head + (size_t)g * 512 + (tid & 7) * 4);
            *reinterpret_cast<float4*>(&Ks[rt * KST + (tid & 7) * 4]) = v;
        }
    }
    if (tid < 169) Rp[tid] = rpb[head * 169 + tid];

    const int tokl = tid >> 2;
    const int q4   = tid & 3;
    const int tr = tokl >> 3, tc = tokl & 7;
    const int i = ti0 + tr, j = tj0 + tc;

    int si = i - 3; si = si < 0 ? 0 : si; si = si > HS - KSZ ? HS - KSZ : si;
    int sj = j - 3; sj = sj < 0 ? 0 : sj; sj = sj > WS - KSZ ? WS - KSZ : sj;

    const int nb0 = (si - gr0) * REG + (sj - gc0);
    const int rb0 = (si - i + 6) * 13 + (sj - j + 6);
    const int tokflat = b * 3136 + i * WS + j;

    const float* qp = qb + (size_t)tokflat * 256 + head * 32 + q4 * 8;
    const float4 qv0 = *reinterpret_cast<const float4*>(qp);
    const float4 qv1 = *reinterpret_cast<const float4*>(qp + 4);

    __syncthreads();

    float lg[49];
    #pragma unroll
    for (int ki = 0; ki < KSZ; ++ki) {
        #pragma unroll
        for (int kj = 0; kj < KSZ; ++kj) {
            const float* kp = &Ks[(nb0 + ki * REG + kj) * KST + q4 * 8];
            const float4 k0 = *reinterpret_cast<const float4*>(kp);
            const float4 k1 = *reinterpret_cast<const float4*>(kp + 4);
            float p = qv0.x * k0.x;
            p = fmaf(qv0.y, k0.y, p);
            p = fmaf(qv0.z, k0.z, p);
            p = fmaf(qv0.w, k0.w, p);
            p = fmaf(qv1.x, k1.x, p);
            p = fmaf(qv1.y, k1.y, p);
            p = fmaf(qv1.z, k1.z, p);
            p = fmaf(qv1.w, k1.w, p);
            p += __shfl_xor(p, 1);
            p += __shfl_xor(p, 2);
            lg[ki * 7 + kj] = p + Rp[rb0 + ki * 13 + kj];
        }
    }

    float m = -1e30f;
    #pragma unroll
    for (int l = 0; l < 49; ++l) m = fmaxf(m, lg[l]);
    float ssum = 0.f;
    #pragma unroll
    for (int l = 0; l < 49; ++l) {
        const float e = __expf(lg[l] - m);
        lg[l] = e;
        ssum += e;
    }

    __syncthreads();   // all K reads done before V overwrites

    #pragma unroll
    for (int rt0 = 0; rt0 < NREG; rt0 += 32) {
        const int rt = rt0 + (tid >> 3);
        if (rt < NREG) {
            const int r = rt / REG, c = rt % REG;
            const int g = (gr0 + r) * WS + (gc0 + c);
            const float4 v = *reinterpret_cast<const float4*>(
                kvb_head + (size_t)g * 512 + 256 + (tid & 7) * 4);
            *reinterpret_cast<float4*>(&Ks[rt * KST + (tid & 7) * 4]) = v;
        }
    }
    __syncthreads();

    float acc[8] = {0.f, 0.f, 0.f, 0.f, 0.f, 0.f, 0.f, 0.f};
    #pragma unroll
    for (int ki = 0; ki < KSZ; ++ki) {
        #pragma unroll
        for (int kj = 0; kj < KSZ; ++kj) {
            const float w = lg[ki * 7 + kj];
            const float* vp = &Ks[(nb0 + ki * REG + kj) * KST + q4 * 8];
            const float4 v0 = *reinterpret_cast<const float4*>(vp);
            const float4 v1 = *reinterpret_cast<const float4*>(vp + 4);
            acc[0] = fmaf(w, v0.x, acc[0]);
            acc[1] = fmaf(w, v0.y, acc[1]);
            acc[2] = fmaf(w, v0.z, acc[2]);
            acc[3] = fmaf(w, v0.w, acc[3]);
            acc[4] = fmaf(w, v1.x, acc[4]);
            acc[5] = fmaf(w, v1.y, acc[5]);
            acc[6] = fmaf(w, v1.z, acc[6]);
            acc[7] = fmaf(w, v1.w, acc[7]);
        }
    }

    const float inv = 1.f / ssum;
    union { u16 u[8]; uint4 v; } ph;
    #pragma unroll
    for (int d = 0; d < 8; ++d)
        ph.u[d] = f2bf(acc[d] * inv);
    // chunk-swizzled store: k = head*32 + q4*8 -> chunk = head*4 + q4
    const int chunk = head * 4 + q4;
    const int seg = chunk >> 3, cin = chunk & 7;
    const int cphys = cin ^ (tokflat & 7);
    const size_t o = (size_t)tokflat * 256 + seg * 64 + cphys * 8;
    *reinterpret_cast<uint4*>(&ohi[o]) = ph.v;
}

// ---------------------------------------------------------------------------
extern "C" void kernel_launch(void* const* d_in, const int* in_sizes, int n_in,
                              void* d_out, int out_size, void* d_ws, size_t ws_size,
                              hipStream_t stream) {
    const float* x_q   = (const float*)d_in[0];
    const float* x_k   = (const float*)d_in[1];
    const float* Wq    = (const float*)d_in[2];
    const float* bq    = (const float*)d_in[3];
    const float* Wkv   = (const float*)d_in[4];
    const float* bkv   = (const float*)d_in[5];
    const float* rpb   = (const float*)d_in[6];
    const float* Wproj = (const float*)d_in[7];
    const float* bproj = (const float*)d_in[8];
    float* out = (float*)d_out;

    const int M = MTOK;

    float* qbuf  = (float*)d_ws;                      // M*256 f32
    float* kvbuf = qbuf + (size_t)M * 256;            // M*512 f32
    u16* at_hi   = (u16*)(kvbuf + (size_t)M * 512);   // M*256 bf16 (swizzled)
    u16* WT      = at_hi + (size_t)M * 256;           // 768*256 (hi)
    u16* WpT_h   = WT + 768 * 256;                    // 256*256
    u16* WpT_l   = WpT_h + 256 * 256;

    const float scale = 0.17677669529663687f;   // 32^-0.5

    dim3 blk(256);
    cvt_w_kernel<<<dim3(256), blk, 0, stream>>>(Wq, Wkv, Wproj, WT, WpT_h, WpT_l);

    // fused q + kv projection, single-pass bf16, f32 outputs
    gemm_qkv_kernel<<<dim3(6 * (M / 64)), blk, 0, stream>>>(
        x_q, x_k, WT, bq, bkv, qbuf, kvbuf, scale);

    // neighborhood attention -> swizzled bf16 (hi only)
    natten_kernel<<<dim3(784), blk, 0, stream>>>(qbuf, kvbuf, rpb, at_hi);

    // out = att @ Wproj + bproj (2-pass: Ah·Bh + Ah·Bl)
    gemm_proj_kernel<<<dim3(4 * (M / 64)), blk, 0, stream>>>(
        at_hi, WpT_h, WpT_l, bproj, out);
}

// Round 13
// 49.487 us; speedup vs baseline: 3.2760x; 1.0296x over previous
//
#include <hip/hip_runtime.h>
#include <hip/hip_bf16.h>

#define NHEAD 8
#define KSZ 7
#define HS 56
#define WS 56
#define MTOK (2 * HS * WS)      // 6272 tokens

typedef unsigned short u16;
typedef unsigned int u32;

using bf16x8 = __attribute__((ext_vector_type(8))) short;
using f32x4  = __attribute__((ext_vector_type(4))) float;

static __device__ __forceinline__ u16 f2bf(float x) {
    u32 u = __float_as_uint(x);
    u += 0x7FFFu + ((u >> 16) & 1u);
    return (u16)(u >> 16);
}
static __device__ __forceinline__ float bf2f(u16 h) {
    return __uint_as_float(((u32)h) << 16);
}
// unpack u32 = (bf16 lo | bf16 hi<<16) -> two floats
static __device__ __forceinline__ float bflo(u32 w) { return __uint_as_float(w << 16); }
static __device__ __forceinline__ float bfhi(u32 w) { return __uint_as_float(w & 0xffff0000u); }

// global -> LDS direct copy, 16B per lane; LDS dest = wave-uniform base + lane*16
static __device__ __forceinline__ void gload16(const void* g, void* l) {
    __builtin_amdgcn_global_load_lds(
        (const __attribute__((address_space(1))) u32*)g,
        (__attribute__((address_space(3))) u32*)l, 16, 0, 0);
}

// bijective XCD-chunked block swizzle (m204)
static __device__ __forceinline__ int xcd_swz(int bid, int nwg) {
    const int q = nwg >> 3, r = nwg & 7;
    const int x = bid & 7, o = bid >> 3;
    return (x < r ? x * (q + 1) : r * (q + 1) + (x - r) * q) + o;
}

// ---------------------------------------------------------------------------
// Weights: W[K][N] fp32 -> WT[N][K] bf16, chunk-swizzled (16B chunk c of row n
// stored at c ^ (n&7) within each 64-elem k-segment).
// Wq -> WT rows 0..255 (hi), Wkv -> WT rows 256..767 (hi), Wproj -> hi + lo.
// ---------------------------------------------------------------------------
__global__ __launch_bounds__(256) void cvt_w_kernel(
    const float* __restrict__ Wq, const float* __restrict__ Wkv,
    const float* __restrict__ Wp,
    u16* __restrict__ WT, u16* __restrict__ WpT_h, u16* __restrict__ WpT_l)
{
    __shared__ float Ts[32][33];
    const int b = blockIdx.x;
    const float* W; u16 *Th, *Tl; int N, tile; bool wantlo;
    if (b < 64)       { W = Wq;  Th = WT;             Tl = nullptr; N = 256; tile = b;       wantlo = false; }
    else if (b < 192) { W = Wkv; Th = WT + 256 * 256; Tl = nullptr; N = 512; tile = b - 64;  wantlo = false; }
    else              { W = Wp;  Th = WpT_h;          Tl = WpT_l;   N = 256; tile = b - 192; wantlo = true; }
    const int ntiles_n = N / 32;
    const int k0 = (tile / ntiles_n) * 32;
    const int n0 = (tile % ntiles_n) * 32;

    const int t = threadIdx.x;
    {
        const int kk = t >> 3, nn4 = (t & 7) * 4;
        float4 v = *reinterpret_cast<const float4*>(&W[(size_t)(k0 + kk) * N + n0 + nn4]);
        Ts[kk][nn4 + 0] = v.x; Ts[kk][nn4 + 1] = v.y;
        Ts[kk][nn4 + 2] = v.z; Ts[kk][nn4 + 3] = v.w;
    }
    __syncthreads();
    {
        const int nn = t >> 3, kk4 = (t & 7) * 4;
        const int n = n0 + nn;
        ushort4 h, l;
        u16* hp = &h.x; u16* lp = &l.x;
        #pragma unroll
        for (int i = 0; i < 4; ++i) {
            float x = Ts[kk4 + i][nn];
            u16 hb = f2bf(x);
            hp[i] = hb;
            lp[i] = f2bf(x - bf2f(hb));
        }
        const int kg = k0 + kk4;
        const int kphys = (kg & ~63) | ((((kg >> 3) & 7) ^ (n & 7)) << 3) | (kg & 7);
        const size_t o = (size_t)n * 256 + kphys;
        *reinterpret_cast<ushort4*>(&Th[o]) = h;
        if (wantlo) *reinterpret_cast<ushort4*>(&Tl[o]) = l;
    }
}

// ---------------------------------------------------------------------------
// Single-pass bf16 MFMA GEMM for the fused q/kv projections.
// 64M x 128N x 64K tile, 4 waves. A-path software-pipelined. B via
// global_load_lds from pre-swizzled WT. OUTPUT bf16 (halves store traffic;
// rounding point validated in Round-10: absmax unchanged at 4.88e-4).
// ---------------------------------------------------------------------------
__global__ __launch_bounds__(256) void gemm_qkv_kernel(
    const float* __restrict__ Aq, const float* __restrict__ Akv,
    const u16* __restrict__ WT,
    const float* __restrict__ biasq, const float* __restrict__ biaskv,
    u16* __restrict__ outq, u16* __restrict__ outkv, float scale)
{
    __shared__ __align__(16) u16 AS[64 * 64];
    __shared__ __align__(16) u16 BS[128 * 64];

    const int tid  = threadIdx.x;
    const int lane = tid & 63;
    const int w    = tid >> 6;          // wave 0..3 -> n-range w*32
    const int l16  = lane & 15;
    const int lhi  = lane >> 4;

    const int swz = xcd_swz(blockIdx.x, 6 * (MTOK / 64));   // 588 blocks
    const int n0 = (swz % 6) * 128;     // 0..767 combined col space
    const int m0 = (swz / 6) * 64;

    const float* A32 = (n0 < 256) ? Aq : Akv;

    const int arow = tid >> 2;
    const int akc  = (tid & 3) * 16;
    const int ac0  = (tid & 3) * 2;
    const int aswz = arow & 7;
    const float* aptr = &A32[(size_t)(m0 + arow) * 256 + akc];

    f32x4 acc[4][2];
    #pragma unroll
    for (int mi = 0; mi < 4; ++mi)
        #pragma unroll
        for (int ni = 0; ni < 2; ++ni) acc[mi][ni] = (f32x4){0.f, 0.f, 0.f, 0.f};

    float4 fa[4];
    #pragma unroll
    for (int v = 0; v < 4; ++v)
        fa[v] = *reinterpret_cast<const float4*>(aptr + v * 4);

    #pragma unroll
    for (int kt = 0; kt < 256; kt += 64) {
        __syncthreads();

        #pragma unroll
        for (int i = 0; i < 4; ++i) {
            const int rbase = w * 32 + i * 8;
            const size_t src = (size_t)(n0 + rbase + (lane >> 3)) * 256 + kt + (lane & 7) * 8;
            gload16(WT + src, &BS[rbase * 64]);
        }

        float4 fn[4];
        if (kt < 192) {
            #pragma unroll
            for (int v = 0; v < 4; ++v)
                fn[v] = *reinterpret_cast<const float4*>(aptr + kt + 64 + v * 4);
        }

        {
            const float f[16] = {fa[0].x, fa[0].y, fa[0].z, fa[0].w,
                                 fa[1].x, fa[1].y, fa[1].z, fa[1].w,
                                 fa[2].x, fa[2].y, fa[2].z, fa[2].w,
                                 fa[3].x, fa[3].y, fa[3].z, fa[3].w};
            union { u16 u[8]; uint4 v; } hx[2];
            #pragma unroll
            for (int e = 0; e < 16; ++e) hx[e >> 3].u[e & 7] = f2bf(f[e]);
            #pragma unroll
            for (int c = 0; c < 2; ++c) {
                const int o = arow * 64 + (((ac0 + c) ^ aswz) << 3);
                *reinterpret_cast<uint4*>(&AS[o]) = hx[c].v;
            }
        }

        __syncthreads();

        #pragma unroll
        for (int ks = 0; ks < 2; ++ks) {
            const int cph = ((ks * 4 + lhi) ^ (l16 & 7)) << 3;
            bf16x8 ah[4], bh[2];
            #pragma unroll
            for (int mi = 0; mi < 4; ++mi)
                ah[mi] = *reinterpret_cast<const bf16x8*>(&AS[(mi * 16 + l16) * 64 + cph]);
            #pragma unroll
            for (int ni = 0; ni < 2; ++ni)
                bh[ni] = *reinterpret_cast<const bf16x8*>(&BS[(w * 32 + ni * 16 + l16) * 64 + cph]);
            #pragma unroll
            for (int mi = 0; mi < 4; ++mi)
                #pragma unroll
                for (int ni = 0; ni < 2; ++ni)
                    acc[mi][ni] = __builtin_amdgcn_mfma_f32_16x16x32_bf16(
                        ah[mi], bh[ni], acc[mi][ni], 0, 0, 0);
        }

        #pragma unroll
        for (int v = 0; v < 4; ++v) fa[v] = fn[v];
    }

    const bool isq = (n0 < 256);
    u16* op = isq ? outq : outkv;
    const float* bs = isq ? biasq : biaskv;
    const int ldo = isq ? 256 : 512;
    const int coff = isq ? 0 : 256;
    const float sc = isq ? scale : 1.0f;

    #pragma unroll
    for (int ni = 0; ni < 2; ++ni) {
        const int col = n0 + w * 32 + ni * 16 + l16 - coff;
        const float bv = bs[col];
        #pragma unroll
        for (int mi = 0; mi < 4; ++mi) {
            const int row = m0 + mi * 16 + lhi * 4;
            #pragma unroll
            for (int rg = 0; rg < 4; ++rg)
                op[(size_t)(row + rg) * ldo + col] = f2bf((acc[mi][ni][rg] + bv) * sc);
        }
    }
}

// ---------------------------------------------------------------------------
// 2-pass hi/lo MFMA GEMM for the output projection (unchanged from Round 12):
//   out ~= Ah·Bh + Ah·Bl
// ---------------------------------------------------------------------------
__global__ __launch_bounds__(256) void gemm_proj_kernel(
    const u16* __restrict__ Ah,
    const u16* __restrict__ Wh, const u16* __restrict__ Wl,
    const float* __restrict__ bias, float* __restrict__ out)
{
    __shared__ __align__(16) u16 AhS[64 * 64];
    __shared__ __align__(16) u16 BhS[64 * 64];
    __shared__ __align__(16) u16 BlS[64 * 64];

    const int tid  = threadIdx.x;
    const int lane = tid & 63;
    const int w    = tid >> 6;
    const int wm   = w >> 1;
    const int wn   = w & 1;
    const int l16  = lane & 15;
    const int lhi  = lane >> 4;

    const int swz = xcd_swz(blockIdx.x, 4 * (MTOK / 64));   // 392 blocks
    const int n0 = (swz % 4) * 64;
    const int m0 = (swz / 4) * 64;

    f32x4 acc[2][2];
    #pragma unroll
    for (int mi = 0; mi < 2; ++mi)
        #pragma unroll
        for (int ni = 0; ni < 2; ++ni) acc[mi][ni] = (f32x4){0.f, 0.f, 0.f, 0.f};

    #pragma unroll
    for (int kt = 0; kt < 256; kt += 64) {
        __syncthreads();

        #pragma unroll
        for (int i = 0; i < 2; ++i) {
            const int rbase = w * 16 + i * 8;
            const size_t srcB = (size_t)(n0 + rbase + (lane >> 3)) * 256 + kt + (lane & 7) * 8;
            const size_t srcA = (size_t)(m0 + rbase + (lane >> 3)) * 256 + kt + (lane & 7) * 8;
            gload16(Wh + srcB, &BhS[rbase * 64]);
            gload16(Wl + srcB, &BlS[rbase * 64]);
            gload16(Ah + srcA, &AhS[rbase * 64]);
        }

        __syncthreads();

        #pragma unroll
        for (int ks = 0; ks < 2; ++ks) {
            const int cph = ((ks * 4 + lhi) ^ (l16 & 7)) << 3;
            bf16x8 ah[2], bh[2], bl[2];
            #pragma unroll
            for (int mi = 0; mi < 2; ++mi)
                ah[mi] = *reinterpret_cast<const bf16x8*>(&AhS[(wm * 32 + mi * 16 + l16) * 64 + cph]);
            #pragma unroll
            for (int ni = 0; ni < 2; ++ni) {
                const int ro = (wn * 32 + ni * 16 + l16) * 64 + cph;
                bh[ni] = *reinterpret_cast<const bf16x8*>(&BhS[ro]);
                bl[ni] = *reinterpret_cast<const bf16x8*>(&BlS[ro]);
            }
            #pragma unroll
            for (int mi = 0; mi < 2; ++mi)
                #pragma unroll
                for (int ni = 0; ni < 2; ++ni) {
                    acc[mi][ni] = __builtin_amdgcn_mfma_f32_16x16x32_bf16(
                        ah[mi], bh[ni], acc[mi][ni], 0, 0, 0);
                    acc[mi][ni] = __builtin_amdgcn_mfma_f32_16x16x32_bf16(
                        ah[mi], bl[ni], acc[mi][ni], 0, 0, 0);
                }
        }
    }

    #pragma unroll
    for (int ni = 0; ni < 2; ++ni) {
        const int col = n0 + wn * 32 + ni * 16 + l16;
        const float bv = bias[col];
        #pragma unroll
        for (int mi = 0; mi < 2; ++mi) {
            const int row = m0 + wm * 32 + mi * 16 + lhi * 4;
            #pragma unroll
            for (int rg = 0; rg < 4; ++rg)
                out[(size_t)(row + rg) * 256 + col] = acc[mi][ni][rg] + bv;
        }
    }
}

// ---------------------------------------------------------------------------
// LDS-tiled neighborhood attention. bf16 GLOBAL q/kv; unpack to f32 during
// LDS staging only — QK/PV inner loops byte-identical to the known-good
// 92-VGPR f32 kernel. Emits chunk-swizzled bf16 (hi) for the 2-pass proj.
// ---------------------------------------------------------------------------
#define REG 14
#define NREG (REG*REG)
#define KST 36

__global__ __launch_bounds__(256) void natten_kernel(
    const u16* __restrict__ qb, const u16* __restrict__ kvb,
    const float* __restrict__ rpb,
    u16* __restrict__ ohi)
{
    __shared__ float Ks[NREG * KST];
    __shared__ float Rp[169];

    const int tid = threadIdx.x;
    const int bid = blockIdx.x;             // 784 blocks
    const int head = bid & 7;
    const int idx  = bid >> 3;
    const int b    = idx / 49;
    const int t49  = idx % 49;
    const int ti0  = (t49 / 7) * 8;
    const int tj0  = (t49 % 7) * 8;

    int gr0 = ti0 - 3; gr0 = gr0 < 0 ? 0 : gr0; gr0 = gr0 > HS - REG ? HS - REG : gr0;
    int gc0 = tj0 - 3; gc0 = gc0 < 0 ? 0 : gc0; gc0 = gc0 > WS - REG ? WS - REG : gc0;

    const u16* kvb_head = kvb + (size_t)b * 3136 * 512 + head * 32;

    // ---- stage K: 4 iters x 64 rows; lane reads 8 bf16 dims (16B), unpacks,
    //      writes 32B f32 to LDS ----
    const int srow = tid >> 2;          // 0..63
    const int sc8  = (tid & 3) * 8;     // dim offset 0/8/16/24
    #pragma unroll
    for (int it = 0; it < 4; ++it) {
        const int rt = it * 64 + srow;
        if (rt < NREG) {
            const int g = (gr0 + rt / REG) * WS + (gc0 + rt % REG);
            const uint4 v = *reinterpret_cast<const uint4*>(
                kvb_head + (size_t)g * 512 + sc8);
            const float4 f0 = make_float4(bflo(v.x), bfhi(v.x), bflo(v.y), bfhi(v.y));
            const float4 f1 = make_float4(bflo(v.z), bfhi(v.z), bflo(v.w), bfhi(v.w));
            *reinterpret_cast<float4*>(&Ks[rt * KST + sc8])     = f0;
            *reinterpret_cast<float4*>(&Ks[rt * KST + sc8 + 4]) = f1;
        }
    }
    if (tid < 169) Rp[tid] = rpb[head * 169 + tid];

    const int tokl = tid >> 2;
    const int q4   = tid & 3;
    const int tr = tokl >> 3, tc = tokl & 7;
    const int i = ti0 + tr, j = tj0 + tc;

    int si = i - 3; si = si < 0 ? 0 : si; si = si > HS - KSZ ? HS - KSZ : si;
    int sj = j - 3; sj = sj < 0 ? 0 : sj; sj = sj > WS - KSZ ? WS - KSZ : sj;

    const int nb0 = (si - gr0) * REG + (sj - gc0);
    const int rb0 = (si - i + 6) * 13 + (sj - j + 6);
    const int tokflat = b * 3136 + i * WS + j;

    // ---- q: bf16 -> f32 regs (same qv0/qv1 as the f32 kernel) ----
    float4 qv0, qv1;
    {
        const uint4 qv = *reinterpret_cast<const uint4*>(
            qb + (size_t)tokflat * 256 + head * 32 + q4 * 8);
        qv0 = make_float4(bflo(qv.x), bfhi(qv.x), bflo(qv.y), bfhi(qv.y));
        qv1 = make_float4(bflo(qv.z), bfhi(qv.z), bflo(qv.w), bfhi(qv.w));
    }

    __syncthreads();

    float lg[49];
    #pragma unroll
    for (int ki = 0; ki < KSZ; ++ki) {
        #pragma unroll
        for (int kj = 0; kj < KSZ; ++kj) {
            const float* kp = &Ks[(nb0 + ki * REG + kj) * KST + q4 * 8];
            const float4 k0 = *reinterpret_cast<const float4*>(kp);
            const float4 k1 = *reinterpret_cast<const float4*>(kp + 4);
            float p = qv0.x * k0.x;
            p = fmaf(qv0.y, k0.y, p);
            p = fmaf(qv0.z, k0.z, p);
            p = fmaf(qv0.w, k0.w, p);
            p = fmaf(qv1.x, k1.x, p);
            p = fmaf(qv1.y, k1.y, p);
            p = fmaf(qv1.z, k1.z, p);
            p = fmaf(qv1.w, k1.w, p);
            p += __shfl_xor(p, 1);
            p += __shfl_xor(p, 2);
            lg[ki * 7 + kj] = p + Rp[rb0 + ki * 13 + kj];
        }
    }

    float m = -1e30f;
    #pragma unroll
    for (int l = 0; l < 49; ++l) m = fmaxf(m, lg[l]);
    float ssum = 0.f;
    #pragma unroll
    for (int l = 0; l < 49; ++l) {
        const float e = __expf(lg[l] - m);
        lg[l] = e;
        ssum += e;
    }

    __syncthreads();   // all K reads done before V overwrites

    // ---- stage V (bf16 -> f32, same buffer) ----
    #pragma unroll
    for (int it = 0; it < 4; ++it) {
        const int rt = it * 64 + srow;
        if (rt < NREG) {
            const int g = (gr0 + rt / REG) * WS + (gc0 + rt % REG);
            const uint4 v = *reinterpret_cast<const uint4*>(
                kvb_head + (size_t)g * 512 + 256 + sc8);
            const float4 f0 = make_float4(bflo(v.x), bfhi(v.x), bflo(v.y), bfhi(v.y));
            const float4 f1 = make_float4(bflo(v.z), bfhi(v.z), bflo(v.w), bfhi(v.w));
            *reinterpret_cast<float4*>(&Ks[rt * KST + sc8])     = f0;
            *reinterpret_cast<float4*>(&Ks[rt * KST + sc8 + 4]) = f1;
        }
    }
    __syncthreads();

    float acc[8] = {0.f, 0.f, 0.f, 0.f, 0.f, 0.f, 0.f, 0.f};
    #pragma unroll
    for (int ki = 0; ki < KSZ; ++ki) {
        #pragma unroll
        for (int kj = 0; kj < KSZ; ++kj) {
            const float w = lg[ki * 7 + kj];
            const float* vp = &Ks[(nb0 + ki * REG + kj) * KST + q4 * 8];
            const float4 v0 = *reinterpret_cast<const float4*>(vp);
            const float4 v1 = *reinterpret_cast<const float4*>(vp + 4);
            acc[0] = fmaf(w, v0.x, acc[0]);
            acc[1] = fmaf(w, v0.y, acc[1]);
            acc[2] = fmaf(w, v0.z, acc[2]);
            acc[3] = fmaf(w, v0.w, acc[3]);
            acc[4] = fmaf(w, v1.x, acc[4]);
            acc[5] = fmaf(w, v1.y, acc[5]);
            acc[6] = fmaf(w, v1.z, acc[6]);
            acc[7] = fmaf(w, v1.w, acc[7]);
        }
    }

    const float inv = 1.f / ssum;
    union { u16 u[8]; uint4 v; } ph;
    #pragma unroll
    for (int d = 0; d < 8; ++d)
        ph.u[d] = f2bf(acc[d] * inv);
    // chunk-swizzled store: k = head*32 + q4*8 -> chunk = head*4 + q4
    const int chunk = head * 4 + q4;
    const int seg = chunk >> 3, cin = chunk & 7;
    const int cphys = cin ^ (tokflat & 7);
    const size_t o = (size_t)tokflat * 256 + seg * 64 + cphys * 8;
    *reinterpret_cast<uint4*>(&ohi[o]) = ph.v;
}

// ---------------------------------------------------------------------------
extern "C" void kernel_launch(void* const* d_in, const int* in_sizes, int n_in,
                              void* d_out, int out_size, void* d_ws, size_t ws_size,
                              hipStream_t stream) {
    const float* x_q   = (const float*)d_in[0];
    const float* x_k   = (const float*)d_in[1];
    const float* Wq    = (const float*)d_in[2];
    const float* bq    = (const float*)d_in[3];
    const float* Wkv   = (const float*)d_in[4];
    const float* bkv   = (const float*)d_in[5];
    const float* rpb   = (const float*)d_in[6];
    const float* Wproj = (const float*)d_in[7];
    const float* bproj = (const float*)d_in[8];
    float* out = (float*)d_out;

    const int M = MTOK;

    u16* qbuf  = (u16*)d_ws;                          // M*256 bf16
    u16* kvbuf = qbuf + (size_t)M * 256;              // M*512 bf16
    u16* at_hi = kvbuf + (size_t)M * 512;             // M*256 bf16 (swizzled)
    u16* WT    = at_hi + (size_t)M * 256;             // 768*256 (hi)
    u16* WpT_h = WT + 768 * 256;                      // 256*256
    u16* WpT_l = WpT_h + 256 * 256;

    const float scale = 0.17677669529663687f;   // 32^-0.5

    dim3 blk(256);
    cvt_w_kernel<<<dim3(256), blk, 0, stream>>>(Wq, Wkv, Wproj, WT, WpT_h, WpT_l);

    // fused q + kv projection, single-pass bf16 -> bf16 outputs
    gemm_qkv_kernel<<<dim3(6 * (M / 64)), blk, 0, stream>>>(
        x_q, x_k, WT, bq, bkv, qbuf, kvbuf, scale);

    // neighborhood attention (bf16 global, f32 LDS) -> swizzled bf16 (hi)
    natten_kernel<<<dim3(784), blk, 0, stream>>>(qbuf, kvbuf, rpb, at_hi);

    // out = att @ Wproj + bproj (2-pass: Ah·Bh + Ah·Bl)
    gemm_proj_kernel<<<dim3(4 * (M / 64)), blk, 0, stream>>>(
        at_hi, WpT_h, WpT_l, bproj, out);
}

// Round 15
// 46.815 us; speedup vs baseline: 3.4630x; 1.0571x over previous
//
#include <hip/hip_runtime.h>
#include <hip/hip_bf16.h>

#define NHEAD 8
#define KSZ 7
#define HS 56
#define WS 56
#define MTOK (2 * HS * WS)      // 6272 tokens

typedef unsigned short u16;
typedef unsigned int u32;

using bf16x8 = __attribute__((ext_vector_type(8))) short;
using f32x4  = __attribute__((ext_vector_type(4))) float;

static __device__ __forceinline__ u16 f2bf(float x) {
    u32 u = __float_as_uint(x);
    u += 0x7FFFu + ((u >> 16) & 1u);
    return (u16)(u >> 16);
}
static __device__ __forceinline__ float bf2f(u16 h) {
    return __uint_as_float(((u32)h) << 16);
}
// unpack u32 = (bf16 lo | bf16 hi<<16) -> two floats
static __device__ __forceinline__ float bflo(u32 w) { return __uint_as_float(w << 16); }
static __device__ __forceinline__ float bfhi(u32 w) { return __uint_as_float(w & 0xffff0000u); }

// intra-quad lane swap on the VALU pipe (DPP quad_perm) — replaces
// __shfl_xor(p,1)/(p,2) which lower to ds_swizzle (LDS pipe).
// xor1: perm(1,0,3,2) = 0xB1; xor2: perm(2,3,0,1) = 0x4E.
template<int CTRL>
static __device__ __forceinline__ float dpp_quad(float p) {
    return __uint_as_float((u32)__builtin_amdgcn_update_dpp(
        0, (int)__float_as_uint(p), CTRL, 0xF, 0xF, true));
}

// global -> LDS direct copy, 16B per lane; LDS dest = wave-uniform base + lane*16
static __device__ __forceinline__ void gload16(const void* g, void* l) {
    __builtin_amdgcn_global_load_lds(
        (const __attribute__((address_space(1))) u32*)g,
        (__attribute__((address_space(3))) u32*)l, 16, 0, 0);
}

// bijective XCD-chunked block swizzle (m204)
static __device__ __forceinline__ int xcd_swz(int bid, int nwg) {
    const int q = nwg >> 3, r = nwg & 7;
    const int x = bid & 7, o = bid >> 3;
    return (x < r ? x * (q + 1) : r * (q + 1) + (x - r) * q) + o;
}

// ---------------------------------------------------------------------------
// Weights: W[K][N] fp32 -> WT[N][K] bf16, chunk-swizzled (16B chunk c of row n
// stored at c ^ (n&7) within each 64-elem k-segment).
// Wq -> WT rows 0..255 (hi), Wkv -> WT rows 256..767 (hi), Wproj -> hi + lo.
// ---------------------------------------------------------------------------
__global__ __launch_bounds__(256) void cvt_w_kernel(
    const float* __restrict__ Wq, const float* __restrict__ Wkv,
    const float* __restrict__ Wp,
    u16* __restrict__ WT, u16* __restrict__ WpT_h, u16* __restrict__ WpT_l)
{
    __shared__ float Ts[32][33];
    const int b = blockIdx.x;
    const float* W; u16 *Th, *Tl; int N, tile; bool wantlo;
    if (b < 64)       { W = Wq;  Th = WT;             Tl = nullptr; N = 256; tile = b;       wantlo = false; }
    else if (b < 192) { W = Wkv; Th = WT + 256 * 256; Tl = nullptr; N = 512; tile = b - 64;  wantlo = false; }
    else              { W = Wp;  Th = WpT_h;          Tl = WpT_l;   N = 256; tile = b - 192; wantlo = true; }
    const int ntiles_n = N / 32;
    const int k0 = (tile / ntiles_n) * 32;
    const int n0 = (tile % ntiles_n) * 32;

    const int t = threadIdx.x;
    {
        const int kk = t >> 3, nn4 = (t & 7) * 4;
        float4 v = *reinterpret_cast<const float4*>(&W[(size_t)(k0 + kk) * N + n0 + nn4]);
        Ts[kk][nn4 + 0] = v.x; Ts[kk][nn4 + 1] = v.y;
        Ts[kk][nn4 + 2] = v.z; Ts[kk][nn4 + 3] = v.w;
    }
    __syncthreads();
    {
        const int nn = t >> 3, kk4 = (t & 7) * 4;
        const int n = n0 + nn;
        ushort4 h, l;
        u16* hp = &h.x; u16* lp = &l.x;
        #pragma unroll
        for (int i = 0; i < 4; ++i) {
            float x = Ts[kk4 + i][nn];
            u16 hb = f2bf(x);
            hp[i] = hb;
            lp[i] = f2bf(x - bf2f(hb));
        }
        const int kg = k0 + kk4;
        const int kphys = (kg & ~63) | ((((kg >> 3) & 7) ^ (n & 7)) << 3) | (kg & 7);
        const size_t o = (size_t)n * 256 + kphys;
        *reinterpret_cast<ushort4*>(&Th[o]) = h;
        if (wantlo) *reinterpret_cast<ushort4*>(&Tl[o]) = l;
    }
}

// ---------------------------------------------------------------------------
// Single-pass bf16 MFMA GEMM for the fused q/kv projections.
// 64M x 128N x 64K tile, 4 waves. A-path software-pipelined. B via
// global_load_lds from pre-swizzled WT. OUTPUT bf16.
// ---------------------------------------------------------------------------
__global__ __launch_bounds__(256) void gemm_qkv_kernel(
    const float* __restrict__ Aq, const float* __restrict__ Akv,
    const u16* __restrict__ WT,
    const float* __restrict__ biasq, const float* __restrict__ biaskv,
    u16* __restrict__ outq, u16* __restrict__ outkv, float scale)
{
    __shared__ __align__(16) u16 AS[64 * 64];
    __shared__ __align__(16) u16 BS[128 * 64];

    const int tid  = threadIdx.x;
    const int lane = tid & 63;
    const int w    = tid >> 6;          // wave 0..3 -> n-range w*32
    const int l16  = lane & 15;
    const int lhi  = lane >> 4;

    const int swz = xcd_swz(blockIdx.x, 6 * (MTOK / 64));   // 588 blocks
    const int n0 = (swz % 6) * 128;     // 0..767 combined col space
    const int m0 = (swz / 6) * 64;

    const float* A32 = (n0 < 256) ? Aq : Akv;

    const int arow = tid >> 2;
    const int akc  = (tid & 3) * 16;
    const int ac0  = (tid & 3) * 2;
    const int aswz = arow & 7;
    const float* aptr = &A32[(size_t)(m0 + arow) * 256 + akc];

    f32x4 acc[4][2];
    #pragma unroll
    for (int mi = 0; mi < 4; ++mi)
        #pragma unroll
        for (int ni = 0; ni < 2; ++ni) acc[mi][ni] = (f32x4){0.f, 0.f, 0.f, 0.f};

    float4 fa[4];
    #pragma unroll
    for (int v = 0; v < 4; ++v)
        fa[v] = *reinterpret_cast<const float4*>(aptr + v * 4);

    #pragma unroll
    for (int kt = 0; kt < 256; kt += 64) {
        __syncthreads();

        #pragma unroll
        for (int i = 0; i < 4; ++i) {
            const int rbase = w * 32 + i * 8;
            const size_t src = (size_t)(n0 + rbase + (lane >> 3)) * 256 + kt + (lane & 7) * 8;
            gload16(WT + src, &BS[rbase * 64]);
        }

        float4 fn[4];
        if (kt < 192) {
            #pragma unroll
            for (int v = 0; v < 4; ++v)
                fn[v] = *reinterpret_cast<const float4*>(aptr + kt + 64 + v * 4);
        }

        {
            const float f[16] = {fa[0].x, fa[0].y, fa[0].z, fa[0].w,
                                 fa[1].x, fa[1].y, fa[1].z, fa[1].w,
                                 fa[2].x, fa[2].y, fa[2].z, fa[2].w,
                                 fa[3].x, fa[3].y, fa[3].z, fa[3].w};
            union { u16 u[8]; uint4 v; } hx[2];
            #pragma unroll
            for (int e = 0; e < 16; ++e) hx[e >> 3].u[e & 7] = f2bf(f[e]);
            #pragma unroll
            for (int c = 0; c < 2; ++c) {
                const int o = arow * 64 + (((ac0 + c) ^ aswz) << 3);
                *reinterpret_cast<uint4*>(&AS[o]) = hx[c].v;
            }
        }

        __syncthreads();

        #pragma unroll
        for (int ks = 0; ks < 2; ++ks) {
            const int cph = ((ks * 4 + lhi) ^ (l16 & 7)) << 3;
            bf16x8 ah[4], bh[2];
            #pragma unroll
            for (int mi = 0; mi < 4; ++mi)
                ah[mi] = *reinterpret_cast<const bf16x8*>(&AS[(mi * 16 + l16) * 64 + cph]);
            #pragma unroll
            for (int ni = 0; ni < 2; ++ni)
                bh[ni] = *reinterpret_cast<const bf16x8*>(&BS[(w * 32 + ni * 16 + l16) * 64 + cph]);
            #pragma unroll
            for (int mi = 0; mi < 4; ++mi)
                #pragma unroll
                for (int ni = 0; ni < 2; ++ni)
                    acc[mi][ni] = __builtin_amdgcn_mfma_f32_16x16x32_bf16(
                        ah[mi], bh[ni], acc[mi][ni], 0, 0, 0);
        }

        #pragma unroll
        for (int v = 0; v < 4; ++v) fa[v] = fn[v];
    }

    const bool isq = (n0 < 256);
    u16* op = isq ? outq : outkv;
    const float* bs = isq ? biasq : biaskv;
    const int ldo = isq ? 256 : 512;
    const int coff = isq ? 0 : 256;
    const float sc = isq ? scale : 1.0f;

    #pragma unroll
    for (int ni = 0; ni < 2; ++ni) {
        const int col = n0 + w * 32 + ni * 16 + l16 - coff;
        const float bv = bs[col];
        #pragma unroll
        for (int mi = 0; mi < 4; ++mi) {
            const int row = m0 + mi * 16 + lhi * 4;
            #pragma unroll
            for (int rg = 0; rg < 4; ++rg)
                op[(size_t)(row + rg) * ldo + col] = f2bf((acc[mi][ni][rg] + bv) * sc);
        }
    }
}

// ---------------------------------------------------------------------------
// 2-pass hi/lo MFMA GEMM for the output projection:
//   out ~= Ah·Bh + Ah·Bl
// ---------------------------------------------------------------------------
__global__ __launch_bounds__(256) void gemm_proj_kernel(
    const u16* __restrict__ Ah,
    const u16* __restrict__ Wh, const u16* __restrict__ Wl,
    const float* __restrict__ bias, float* __restrict__ out)
{
    __shared__ __align__(16) u16 AhS[64 * 64];
    __shared__ __align__(16) u16 BhS[64 * 64];
    __shared__ __align__(16) u16 BlS[64 * 64];

    const int tid  = threadIdx.x;
    const int lane = tid & 63;
    const int w    = tid >> 6;
    const int wm   = w >> 1;
    const int wn   = w & 1;
    const int l16  = lane & 15;
    const int lhi  = lane >> 4;

    const int swz = xcd_swz(blockIdx.x, 4 * (MTOK / 64));   // 392 blocks
    const int n0 = (swz % 4) * 64;
    const int m0 = (swz / 4) * 64;

    f32x4 acc[2][2];
    #pragma unroll
    for (int mi = 0; mi < 2; ++mi)
        #pragma unroll
        for (int ni = 0; ni < 2; ++ni) acc[mi][ni] = (f32x4){0.f, 0.f, 0.f, 0.f};

    #pragma unroll
    for (int kt = 0; kt < 256; kt += 64) {
        __syncthreads();

        #pragma unroll
        for (int i = 0; i < 2; ++i) {
            const int rbase = w * 16 + i * 8;
            const size_t srcB = (size_t)(n0 + rbase + (lane >> 3)) * 256 + kt + (lane & 7) * 8;
            const size_t srcA = (size_t)(m0 + rbase + (lane >> 3)) * 256 + kt + (lane & 7) * 8;
            gload16(Wh + srcB, &BhS[rbase * 64]);
            gload16(Wl + srcB, &BlS[rbase * 64]);
            gload16(Ah + srcA, &AhS[rbase * 64]);
        }

        __syncthreads();

        #pragma unroll
        for (int ks = 0; ks < 2; ++ks) {
            const int cph = ((ks * 4 + lhi) ^ (l16 & 7)) << 3;
            bf16x8 ah[2], bh[2], bl[2];
            #pragma unroll
            for (int mi = 0; mi < 2; ++mi)
                ah[mi] = *reinterpret_cast<const bf16x8*>(&AhS[(wm * 32 + mi * 16 + l16) * 64 + cph]);
            #pragma unroll
            for (int ni = 0; ni < 2; ++ni) {
                const int ro = (wn * 32 + ni * 16 + l16) * 64 + cph;
                bh[ni] = *reinterpret_cast<const bf16x8*>(&BhS[ro]);
                bl[ni] = *reinterpret_cast<const bf16x8*>(&BlS[ro]);
            }
            #pragma unroll
            for (int mi = 0; mi < 2; ++mi)
                #pragma unroll
                for (int ni = 0; ni < 2; ++ni) {
                    acc[mi][ni] = __builtin_amdgcn_mfma_f32_16x16x32_bf16(
                        ah[mi], bh[ni], acc[mi][ni], 0, 0, 0);
                    acc[mi][ni] = __builtin_amdgcn_mfma_f32_16x16x32_bf16(
                        ah[mi], bl[ni], acc[mi][ni], 0, 0, 0);
                }
        }
    }

    #pragma unroll
    for (int ni = 0; ni < 2; ++ni) {
        const int col = n0 + wn * 32 + ni * 16 + l16;
        const float bv = bias[col];
        #pragma unroll
        for (int mi = 0; mi < 2; ++mi) {
            const int row = m0 + wm * 32 + mi * 16 + lhi * 4;
            #pragma unroll
            for (int rg = 0; rg < 4; ++rg)
                out[(size_t)(row + rg) * 256 + col] = acc[mi][ni][rg] + bv;
        }
    }
}

// ---------------------------------------------------------------------------
// LDS-tiled neighborhood attention. bf16 GLOBAL q/kv; unpack to f32 during
// LDS staging only. Quad reduces via DPP (VALU pipe) instead of shfl (LDS
// pipe) — bitwise-identical arithmetic. Emits chunk-swizzled bf16 (hi).
// ---------------------------------------------------------------------------
#define REG 14
#define NREG (REG*REG)
#define KST 36

__global__ __launch_bounds__(256) void natten_kernel(
    const u16* __restrict__ qb, const u16* __restrict__ kvb,
    const float* __restrict__ rpb,
    u16* __restrict__ ohi)
{
    __shared__ float Ks[NREG * KST];
    __shared__ float Rp[169];

    const int tid = threadIdx.x;
    const int bid = blockIdx.x;             // 784 blocks
    const int head = bid & 7;
    const int idx  = bid >> 3;
    const int b    = idx / 49;
    const int t49  = idx % 49;
    const int ti0  = (t49 / 7) * 8;
    const int tj0  = (t49 % 7) * 8;

    int gr0 = ti0 - 3; gr0 = gr0 < 0 ? 0 : gr0; gr0 = gr0 > HS - REG ? HS - REG : gr0;
    int gc0 = tj0 - 3; gc0 = gc0 < 0 ? 0 : gc0; gc0 = gc0 > WS - REG ? WS - REG : gc0;

    const u16* kvb_head = kvb + (size_t)b * 3136 * 512 + head * 32;

    // ---- stage K: 4 iters x 64 rows; lane reads 8 bf16 dims (16B), unpacks,
    //      writes 32B f32 to LDS ----
    const int srow = tid >> 2;          // 0..63
    const int sc8  = (tid & 3) * 8;     // dim offset 0/8/16/24
    #pragma unroll
    for (int it = 0; it < 4; ++it) {
        const int rt = it * 64 + srow;
        if (rt < NREG) {
            const int g = (gr0 + rt / REG) * WS + (gc0 + rt % REG);
            const uint4 v = *reinterpret_cast<const uint4*>(
                kvb_head + (size_t)g * 512 + sc8);
            const float4 f0 = make_float4(bflo(v.x), bfhi(v.x), bflo(v.y), bfhi(v.y));
            const float4 f1 = make_float4(bflo(v.z), bfhi(v.z), bflo(v.w), bfhi(v.w));
            *reinterpret_cast<float4*>(&Ks[rt * KST + sc8])     = f0;
            *reinterpret_cast<float4*>(&Ks[rt * KST + sc8 + 4]) = f1;
        }
    }
    if (tid < 169) Rp[tid] = rpb[head * 169 + tid];

    const int tokl = tid >> 2;
    const int q4   = tid & 3;
    const int tr = tokl >> 3, tc = tokl & 7;
    const int i = ti0 + tr, j = tj0 + tc;

    int si = i - 3; si = si < 0 ? 0 : si; si = si > HS - KSZ ? HS - KSZ : si;
    int sj = j - 3; sj = sj < 0 ? 0 : sj; sj = sj > WS - KSZ ? WS - KSZ : sj;

    const int nb0 = (si - gr0) * REG + (sj - gc0);
    const int rb0 = (si - i + 6) * 13 + (sj - j + 6);
    const int tokflat = b * 3136 + i * WS + j;

    // ---- q: bf16 -> f32 regs ----
    float4 qv0, qv1;
    {
        const uint4 qv = *reinterpret_cast<const uint4*>(
            qb + (size_t)tokflat * 256 + head * 32 + q4 * 8);
        qv0 = make_float4(bflo(qv.x), bfhi(qv.x), bflo(qv.y), bfhi(qv.y));
        qv1 = make_float4(bflo(qv.z), bfhi(qv.z), bflo(qv.w), bfhi(qv.w));
    }

    __syncthreads();

    float lg[49];
    #pragma unroll
    for (int ki = 0; ki < KSZ; ++ki) {
        #pragma unroll
        for (int kj = 0; kj < KSZ; ++kj) {
            const float* kp = &Ks[(nb0 + ki * REG + kj) * KST + q4 * 8];
            const float4 k0 = *reinterpret_cast<const float4*>(kp);
            const float4 k1 = *reinterpret_cast<const float4*>(kp + 4);
            float p = qv0.x * k0.x;
            p = fmaf(qv0.y, k0.y, p);
            p = fmaf(qv0.z, k0.z, p);
            p = fmaf(qv0.w, k0.w, p);
            p = fmaf(qv1.x, k1.x, p);
            p = fmaf(qv1.y, k1.y, p);
            p = fmaf(qv1.z, k1.z, p);
            p = fmaf(qv1.w, k1.w, p);
            p += dpp_quad<0xB1>(p);    // xor 1 within quad (VALU pipe)
            p += dpp_quad<0x4E>(p);    // xor 2 within quad (VALU pipe)
            lg[ki * 7 + kj] = p + Rp[rb0 + ki * 13 + kj];
        }
    }

    float m = -1e30f;
    #pragma unroll
    for (int l = 0; l < 49; ++l) m = fmaxf(m, lg[l]);
    float ssum = 0.f;
    #pragma unroll
    for (int l = 0; l < 49; ++l) {
        const float e = __expf(lg[l] - m);
        lg[l] = e;
        ssum += e;
    }

    __syncthreads();   // all K reads done before V overwrites

    // ---- stage V (bf16 -> f32, same buffer) ----
    #pragma unroll
    for (int it = 0; it < 4; ++it) {
        const int rt = it * 64 + srow;
        if (rt < NREG) {
            const int g = (gr0 + rt / REG) * WS + (gc0 + rt % REG);
            const uint4 v = *reinterpret_cast<const uint4*>(
                kvb_head + (size_t)g * 512 + 256 + sc8);
            const float4 f0 = make_float4(bflo(v.x), bfhi(v.x), bflo(v.y), bfhi(v.y));
            const float4 f1 = make_float4(bflo(v.z), bfhi(v.z), bflo(v.w), bfhi(v.w));
            *reinterpret_cast<float4*>(&Ks[rt * KST + sc8])     = f0;
            *reinterpret_cast<float4*>(&Ks[rt * KST + sc8 + 4]) = f1;
        }
    }
    __syncthreads();

    float acc[8] = {0.f, 0.f, 0.f, 0.f, 0.f, 0.f, 0.f, 0.f};
    #pragma unroll
    for (int ki = 0; ki < KSZ; ++ki) {
        #pragma unroll
        for (int kj = 0; kj < KSZ; ++kj) {
            const float w = lg[ki * 7 + kj];
            const float* vp = &Ks[(nb0 + ki * REG + kj) * KST + q4 * 8];
            const float4 v0 = *reinterpret_cast<const float4*>(vp);
            const float4 v1 = *reinterpret_cast<const float4*>(vp + 4);
            acc[0] = fmaf(w, v0.x, acc[0]);
            acc[1] = fmaf(w, v0.y, acc[1]);
            acc[2] = fmaf(w, v0.z, acc[2]);
            acc[3] = fmaf(w, v0.w, acc[3]);
            acc[4] = fmaf(w, v1.x, acc[4]);
            acc[5] = fmaf(w, v1.y, acc[5]);
            acc[6] = fmaf(w, v1.z, acc[6]);
            acc[7] = fmaf(w, v1.w, acc[7]);
        }
    }

    const float inv = 1.f / ssum;
    union { u16 u[8]; uint4 v; } ph;
    #pragma unroll
    for (int d = 0; d < 8; ++d)
        ph.u[d] = f2bf(acc[d] * inv);
    // chunk-swizzled store: k = head*32 + q4*8 -> chunk = head*4 + q4
    const int chunk = head * 4 + q4;
    const int seg = chunk >> 3, cin = chunk & 7;
    const int cphys = cin ^ (tokflat & 7);
    const size_t o = (size_t)tokflat * 256 + seg * 64 + cphys * 8;
    *reinterpret_cast<uint4*>(&ohi[o]) = ph.v;
}

// ---------------------------------------------------------------------------
extern "C" void kernel_launch(void* const* d_in, const int* in_sizes, int n_in,
                              void* d_out, int out_size, void* d_ws, size_t ws_size,
                              hipStream_t stream) {
    const float* x_q   = (const float*)d_in[0];
    const float* x_k   = (const float*)d_in[1];
    const float* Wq    = (const float*)d_in[2];
    const float* bq    = (const float*)d_in[3];
    const float* Wkv   = (const float*)d_in[4];
    const float* bkv   = (const float*)d_in[5];
    const float* rpb   = (const float*)d_in[6];
    const float* Wproj = (const float*)d_in[7];
    const float* bproj = (const float*)d_in[8];
    float* out = (float*)d_out;

    const int M = MTOK;

    u16* qbuf  = (u16*)d_ws;                          // M*256 bf16
    u16* kvbuf = qbuf + (size_t)M * 256;              // M*512 bf16
    u16* at_hi = kvbuf + (size_t)M * 512;             // M*256 bf16 (swizzled)
    u16* WT    = at_hi + (size_t)M * 256;             // 768*256 (hi)
    u16* WpT_h = WT + 768 * 256;                      // 256*256
    u16* WpT_l = WpT_h + 256 * 256;

    const float scale = 0.17677669529663687f;   // 32^-0.5

    dim3 blk(256);
    cvt_w_kernel<<<dim3(256), blk, 0, stream>>>(Wq, Wkv, Wproj, WT, WpT_h, WpT_l);

    // fused q + kv projection, single-pass bf16 -> bf16 outputs
    gemm_qkv_kernel<<<dim3(6 * (M / 64)), blk, 0, stream>>>(
        x_q, x_k, WT, bq, bkv, qbuf, kvbuf, scale);

    // neighborhood attention (bf16 global, f32 LDS, DPP reduces) -> bf16 hi
    natten_kernel<<<dim3(784), blk, 0, stream>>>(qbuf, kvbuf, rpb, at_hi);

    // out = att @ Wproj + bproj (2-pass: Ah·Bh + Ah·Bl)
    gemm_proj_kernel<<<dim3(4 * (M / 64)), blk, 0, stream>>>(
        at_hi, WpT_h, WpT_l, bproj, out);
}